// Round 1
// baseline (371.728 us; speedup 1.0000x reference)
//
#include <hip/hip_runtime.h>

// Fokker-Planck 2D step, B=128, Nx=Ny=512, f32, 9-point stencil.
// Memory-bound: ideal HBM traffic ~273 MB -> ~43 us at 6.3 TB/s.

namespace {

constexpr int N   = 512;        // Nx == Ny
constexpr long NN = (long)N * N;
constexpr int SPR = N / 4;      // float4 strips per row = 128

__device__ __forceinline__ float4 ld4(const float* __restrict__ p) {
    return *reinterpret_cast<const float4*>(p);
}

struct W6 { float v[6]; };   // cols j0-1 .. j0+4

// Load a 6-wide window of one row: aligned float4 center + masked halo scalars.
// jl/jr are pre-clamped indices, mL/mR zero the out-of-grid halos (vacuum BC).
__device__ __forceinline__ W6 load6(const float* __restrict__ row, int j0,
                                    int jl, int jr, float mL, float mR) {
    W6 w;
    const float4 c = ld4(row + j0);
    w.v[0] = row[jl] * mL;
    w.v[1] = c.x; w.v[2] = c.y; w.v[3] = c.z; w.v[4] = c.w;
    w.v[5] = row[jr] * mR;
    return w;
}

__device__ __forceinline__ void unpack4(float* d, float4 t) {
    d[0] = t.x; d[1] = t.y; d[2] = t.z; d[3] = t.w;
}

} // namespace

extern "C" __global__ __launch_bounds__(256) void fp2d_step(
    const float* __restrict__ f,     // (B, N, N)
    const float* __restrict__ A,     // (2, N, N)  [Ax, Ay]
    const float* __restrict__ D,     // (3, N, N)  [Dxx, Dyy, Dxy]
    const float* __restrict__ dtp,   // scalar
    float* __restrict__ out)         // (B, N, N)
{
    // --- XCD-chunked bijective swizzle (T1): contiguous grid chunk per XCD so
    // adjacent block-rows (sharing f halo rows) hit the same XCD L2.
    int bid = (int)blockIdx.x;
    {
        const int nwg = (int)gridDim.x;
        const int nx = 8;
        const int chunk = nwg / nx;
        if (chunk * nx == nwg) bid = (bid % nx) * chunk + (bid / nx);
    }

    const long tid = (long)bid * 256 + threadIdx.x;
    const int  s   = (int)(tid % SPR);
    const int  i   = (int)((tid / SPR) % N);
    const int  b   = (int)(tid / ((long)SPR * N));
    const int  j0  = s * 4;

    const float dt = dtp[0];   // wave-uniform -> scalar load

    // Row clamps + vacuum masks (branch-free; wave-uniform in i).
    const int   im = (i > 0)     ? i - 1 : 0;
    const int   ip = (i < N - 1) ? i + 1 : N - 1;
    const float mm = (i > 0)     ? 1.f : 0.f;
    const float mp = (i < N - 1) ? 1.f : 0.f;
    const int   jl = (j0 > 0)      ? j0 - 1 : 0;
    const int   jr = (j0 + 4 < N)  ? j0 + 4 : N - 1;
    const float mL = (j0 > 0)      ? 1.f : 0.f;
    const float mR = (j0 + 4 < N)  ? 1.f : 0.f;

    // --- f windows (3 rows x 6 cols), out-of-grid rows zeroed.
    const float* fb  = f + b * NN;
    W6 fm = load6(fb + (long)im * N, j0, jl, jr, mL, mR);
    W6 fc = load6(fb + (long)i  * N, j0, jl, jr, mL, mR);
    W6 fp = load6(fb + (long)ip * N, j0, jl, jr, mL, mR);
#pragma unroll
    for (int k = 0; k < 6; ++k) { fm.v[k] *= mm; fp.v[k] *= mp; }

    // --- coefficient windows (batch-independent -> L2/L3-resident).
    const float* A0 = A;
    const float* A1 = A + NN;
    const float* D0 = D;
    const float* D1 = D + NN;
    const float* D2 = D + 2 * NN;

    float a0m[4], a0p[4], d0m[4], d0c[4], d0p[4];
    unpack4(a0m, ld4(A0 + (long)im * N + j0));
    unpack4(a0p, ld4(A0 + (long)ip * N + j0));
    unpack4(d0m, ld4(D0 + (long)im * N + j0));
    unpack4(d0c, ld4(D0 + (long)i  * N + j0));
    unpack4(d0p, ld4(D0 + (long)ip * N + j0));
    const W6 a1  = load6(A1 + (long)i  * N, j0, jl, jr, mL, mR);
    const W6 d1  = load6(D1 + (long)i  * N, j0, jl, jr, mL, mR);
    const W6 d2m = load6(D2 + (long)im * N, j0, jl, jr, mL, mR);
    const W6 d2p = load6(D2 + (long)ip * N, j0, jl, jr, mL, mR);

    // --- stencil. Coefficients live at the NEIGHBOR point (shift(A*f)).
    float r[4];
#pragma unroll
    for (int k = 0; k < 4; ++k) {
        const float fL  = fc.v[k], fC  = fc.v[k + 1], fR  = fc.v[k + 2];
        const float fmL = fm.v[k], fmC = fm.v[k + 1], fmR = fm.v[k + 2];
        const float fpL = fp.v[k], fpC = fp.v[k + 1], fpR = fp.v[k + 2];

        float rhs;
        // -dFx = -0.5*(Ax[i+1,j]*f[i+1,j] - Ax[i-1,j]*f[i-1,j])
        rhs  = -0.5f * (a0p[k] * fpC - a0m[k] * fmC);
        // -dFy
        rhs -= 0.5f * (a1.v[k + 2] * fR - a1.v[k] * fL);
        // +0.5*d2Gxx
        rhs += 0.5f * (d0p[k] * fpC - 2.f * d0c[k] * fC + d0m[k] * fmC);
        // +0.5*d2Gyy
        rhs += 0.5f * (d1.v[k + 2] * fR - 2.f * d1.v[k + 1] * fC + d1.v[k] * fL);
        // +d2Gxy
        rhs += 0.25f * (d2p.v[k + 2] * fpR - d2p.v[k] * fpL
                      - d2m.v[k + 2] * fmR + d2m.v[k] * fmL);

        const float val = fC + dt * rhs;
        r[k] = val > 0.f ? val : 0.f;
    }

    float4 o;
    o.x = r[0]; o.y = r[1]; o.z = r[2]; o.w = r[3];
    *reinterpret_cast<float4*>(out + b * NN + (long)i * N + j0) = o;
}

extern "C" void kernel_launch(void* const* d_in, const int* in_sizes, int n_in,
                              void* d_out, int out_size, void* d_ws, size_t ws_size,
                              hipStream_t stream) {
    const float* f   = (const float*)d_in[0];
    const float* A   = (const float*)d_in[1];
    const float* D   = (const float*)d_in[2];
    const float* dtp = (const float*)d_in[3];
    float* out = (float*)d_out;

    const int B = in_sizes[0] / (int)NN;          // 128
    const long threads = (long)B * N * SPR;       // one thread per float4 strip
    const unsigned grid = (unsigned)(threads / 256);  // B*65536/256 -> exact

    hipLaunchKernelGGL(fp2d_step, dim3(grid), dim3(256), 0, stream,
                       f, A, D, dtp, out);
}

// Round 2
// 329.530 us; speedup vs baseline: 1.1281x; 1.1281x over previous
//
#include <hip/hip_runtime.h>

// Fokker-Planck 2D step, B=128, Nx=Ny=512, f32, 9-point stencil.
// Register-rolling column kernel: each thread produces T=8 rows of one
// float4-wide column strip; the 3-row stencil windows roll through registers
// so each f row is fetched (T+2)/T = 1.125x instead of 3x.
// Block = 256 threads = full 512-wide row x 2 row-groups -> 16-row band.
// Grid order = band-major over batches: all 128 batches of a band run
// back-to-back so the band's coefficient rows stay L2-resident.

namespace {

constexpr int N   = 512;
constexpr long NN = (long)N * N;
constexpr int SPR = N / 4;     // 128 float4 strips per row
constexpr int T   = 8;         // rows per thread
constexpr int BANDS = N / (2 * T);   // 32 bands of 16 rows

typedef float f4 __attribute__((ext_vector_type(4)));

__device__ __forceinline__ float4 ld4(const float* __restrict__ p) {
    return *reinterpret_cast<const float4*>(p);
}

struct W6 { float v[6]; };   // cols j0-1 .. j0+4

__device__ __forceinline__ W6 load6(const float* __restrict__ row, int j0,
                                    int jl, int jr, float mL, float mR) {
    W6 w;
    const float4 c = ld4(row + j0);
    w.v[0] = row[jl] * mL;
    w.v[1] = c.x; w.v[2] = c.y; w.v[3] = c.z; w.v[4] = c.w;
    w.v[5] = row[jr] * mR;
    return w;
}

struct C4 { float v[4]; };
__device__ __forceinline__ C4 ldc4(const float* __restrict__ p) {
    const float4 t = ld4(p);
    C4 c; c.v[0] = t.x; c.v[1] = t.y; c.v[2] = t.z; c.v[3] = t.w;
    return c;
}

} // namespace

extern "C" __global__ __launch_bounds__(256) void fp2d_step(
    const float* __restrict__ f,     // (B, N, N)
    const float* __restrict__ A,     // (2, N, N)  [Ax, Ay]
    const float* __restrict__ D,     // (3, N, N)  [Dxx, Dyy, Dxy]
    const float* __restrict__ dtp,   // scalar
    float* __restrict__ out)         // (B, N, N)
{
    // Band-major ordering: blocks [band*128 .. band*128+127] cover all
    // batches of one 16-row band -> that band's coefficients stay hot in L2.
    const int blk  = (int)blockIdx.x;
    const int band = blk >> 7;           // / 128 batches
    const int b    = blk & 127;

    const int s  = (int)threadIdx.x & (SPR - 1);   // strip in row
    const int rg = (int)threadIdx.x >> 7;          // row-group 0/1 (wave-uniform)
    const int i0 = (band * 2 + rg) * T;            // first output row
    const int j0 = s * 4;

    const float dt = dtp[0];

    // Column halo (per-thread constant).
    const int   jl = (j0 > 0)     ? j0 - 1 : 0;
    const int   jr = (j0 + 4 < N) ? j0 + 4 : N - 1;
    const float mL = (j0 > 0)     ? 1.f : 0.f;
    const float mR = (j0 + 4 < N) ? 1.f : 0.f;

    const float* fb = f + (long)b * NN;
    const float* A0 = A;
    const float* A1 = A + NN;
    const float* D0 = D;
    const float* D1 = D + NN;
    const float* D2 = D + 2 * NN;

    // ---- prologue: rows i0-1 (masked if outside) and i0.
    const int   im0 = (i0 > 0) ? i0 - 1 : 0;
    const float mm0 = (i0 > 0) ? 1.f : 0.f;

    W6 fm = load6(fb + (long)im0 * N, j0, jl, jr, mL, mR);
#pragma unroll
    for (int k = 0; k < 6; ++k) fm.v[k] *= mm0;
    W6 fc = load6(fb + (long)i0 * N, j0, jl, jr, mL, mR);

    C4 a0m = ldc4(A0 + (long)im0 * N + j0);
    C4 a0c = ldc4(A0 + (long)i0  * N + j0);
    C4 d0m = ldc4(D0 + (long)im0 * N + j0);
    C4 d0c = ldc4(D0 + (long)i0  * N + j0);
    W6 d2m = load6(D2 + (long)im0 * N, j0, jl, jr, mL, mR);
    W6 d2c = load6(D2 + (long)i0  * N, j0, jl, jr, mL, mR);

    float* ob = out + (long)b * NN + (long)i0 * N + j0;

    // ---- T rolling steps.
#pragma unroll
    for (int t = 0; t < T; ++t) {
        const int   i   = i0 + t;
        const int   ipr = (i + 1 < N) ? i + 1 : N - 1;
        const float mp  = (i + 1 < N) ? 1.f : 0.f;

        W6 fp = load6(fb + (long)ipr * N, j0, jl, jr, mL, mR);
#pragma unroll
        for (int k = 0; k < 6; ++k) fp.v[k] *= mp;

        const C4 a0p = ldc4(A0 + (long)ipr * N + j0);
        const C4 d0p = ldc4(D0 + (long)ipr * N + j0);
        const W6 d2p = load6(D2 + (long)ipr * N, j0, jl, jr, mL, mR);
        const W6 a1  = load6(A1 + (long)i   * N, j0, jl, jr, mL, mR);
        const W6 d1  = load6(D1 + (long)i   * N, j0, jl, jr, mL, mR);

        f4 o;
#pragma unroll
        for (int k = 0; k < 4; ++k) {
            const float fL  = fc.v[k], fC  = fc.v[k + 1], fR  = fc.v[k + 2];
            const float fmL = fm.v[k], fmC = fm.v[k + 1], fmR = fm.v[k + 2];
            const float fpL = fp.v[k], fpC = fp.v[k + 1], fpR = fp.v[k + 2];

            float rhs;
            // -dFx
            rhs  = -0.5f * (a0p.v[k] * fpC - a0m.v[k] * fmC);
            // -dFy
            rhs -= 0.5f * (a1.v[k + 2] * fR - a1.v[k] * fL);
            // +0.5*d2Gxx
            rhs += 0.5f * (d0p.v[k] * fpC - 2.f * d0c.v[k] * fC + d0m.v[k] * fmC);
            // +0.5*d2Gyy
            rhs += 0.5f * (d1.v[k + 2] * fR - 2.f * d1.v[k + 1] * fC + d1.v[k] * fL);
            // +d2Gxy
            rhs += 0.25f * (d2p.v[k + 2] * fpR - d2p.v[k] * fpL
                          - d2m.v[k + 2] * fmR + d2m.v[k] * fmL);

            const float val = fC + dt * rhs;
            o[k] = val > 0.f ? val : 0.f;
        }

        // out is never re-read: nontemporal store, keep L2/L3 for f + coeffs.
        __builtin_nontemporal_store(o, reinterpret_cast<f4*>(ob));
        ob += N;

        // roll windows down one row
        fm  = fc;  fc  = fp;
        a0m = a0c; a0c = a0p;
        d0m = d0c; d0c = d0p;
        d2m = d2c; d2c = d2p;
    }
}

extern "C" void kernel_launch(void* const* d_in, const int* in_sizes, int n_in,
                              void* d_out, int out_size, void* d_ws, size_t ws_size,
                              hipStream_t stream) {
    const float* f   = (const float*)d_in[0];
    const float* A   = (const float*)d_in[1];
    const float* D   = (const float*)d_in[2];
    const float* dtp = (const float*)d_in[3];
    float* out = (float*)d_out;

    const int B = in_sizes[0] / (int)NN;            // 128
    const unsigned grid = (unsigned)(BANDS * B);    // 32 bands * 128 batches = 4096

    hipLaunchKernelGGL(fp2d_step, dim3(grid), dim3(256), 0, stream,
                       f, A, D, dtp, out);
}